// Round 16
// baseline (23180.603 us; speedup 1.0000x reference)
//
#include <hip/hip_runtime.h>
#include <stdint.h>

// Seq2Seq decoder (2-layer LSTM + Luong attention), B=64, T=256, S=512, H=512.
// Round 16: R15 (18.38ms) + k_attn TLP fix:
//  - k_attn grid 256 -> 512 (b x 8 s-groups of 64 rows): 2 WGs/CU -> 4 waves/
//    SIMD on the 67MB/step L3 stream (was 2 -> latency-exposed)
//  - 2-deep row prefetch (was 1-deep)
//  - k_out: 8-way softmax combine (R11 pattern), part_ctx 8 planes
// Merge analysis exhausted: every phase boundary is all-to-all; redundant-
// compute merges force 512MB/step weight streams (worse than the saved gap).
// All-f32 datapath (chaos: 2^-23 noise amplifies ~1e5x; bf16 impossible).

typedef float f32x4 __attribute__((ext_vector_type(4)));

struct Params {
  const float* tgtT4;   // [256][128][64][4]
  const float* mask;    // [64][512] (1.0 = masked)
  const float* b1;      // [2048]
  const float* b2;      // [2048]
  const float* Wm;      // [1024][512] raw (row n = weights for q col n)
  const float* enc;     // [64][512][1024]
  const float* W1T;     // [2048][1536]
  const float* W2T;     // [2048][1024]
  const float* WaT;     // [512][1536]
  float *h1a,*h1b,*h2a,*h2b;   // T4 [128][64][4]
  float *attnT4;               // T4 [128][64][4]
  float *q;                    // [64][1024]
  float *c1,*c2;               // [64][512]
  float *eh2;                  // [64][512]
  float *part_ctx;             // [8][256][64][4]
  float *part_ml;              // [64][8][2]
  uint32_t *pktab;             // [64][8][8] packed unmasked-row lists (8x4bit)
  int      *natab;             // [64][8][8] active counts
  float *out;                  // [64][256][512]
};

__device__ __forceinline__ float sigmf(float x){ return 1.f/(1.f+__expf(-x)); }

// -------- GEMM core: out[c][b] += sum_k act[k][b] * wL[c][k] --------
template<int NCOLS, int KGW, int KST>
__device__ __forceinline__ void mm_core(const float* seg0, const float* seg1, const float* seg2,
                                        const float* wL, float* zb, int lane, int wv){
  float acc[NCOLS];
  #pragma unroll
  for (int c=0;c<NCOLS;++c) acc[c]=0.f;
  const int kg0 = wv*KGW;
  #pragma unroll 4
  for (int i=0;i<KGW;++i){
    const int kg = kg0 + i;
    const float* bp = (kg<128) ? seg0 : ((kg<256) ? seg1 : seg2);
    f32x4 a = *(const f32x4*)(bp + ((size_t)kg<<8) + (lane<<2));
    #pragma unroll
    for (int c=0;c<NCOLS;++c){
      f32x4 w = *(const f32x4*)(wL + c*KST + (kg<<2));
      acc[c] = fmaf(a[0],w[0],acc[c]); acc[c] = fmaf(a[1],w[1],acc[c]);
      acc[c] = fmaf(a[2],w[2],acc[c]); acc[c] = fmaf(a[3],w[3],acc[c]);
    }
  }
  #pragma unroll
  for (int c=0;c<NCOLS;++c) zb[(wv*NCOLS+c)*64 + lane] = acc[c];
}

// ======== K1/K2: LSTM layers (grid 256, 512 thr; WG owns 2 h-cols) ========
template<int PHASE>
__global__ __launch_bounds__(512, 2)
void k_lstm(Params P, int t, int rp){
  constexpr int KF  = (PHASE==1) ? 1536 : 1024;
  constexpr int KGW = (PHASE==1) ? 48 : 32;
  constexpr int KQ  = KF/4;
  __shared__ float smem[8*KF + 4096 + 512];
  float* zb = smem + 8*KF;
  float* zs = zb + 4096;
  const int wg=blockIdx.x, tid=threadIdx.x, lane=tid&63, wv=tid>>6;
  const float* WT = (PHASE==1) ? P.W1T : P.W2T;
  #pragma unroll
  for (int c=0;c<8;++c){
    const int n = ((c>>1)<<9) + (wg<<1) + (c&1);
    const f32x4* src = (const f32x4*)(WT + (size_t)n*KF);
    f32x4* dst = (f32x4*)(smem + c*KF);
    if (tid < KQ) dst[tid] = src[tid];
  }
  __syncthreads();

  const float* h1r = rp ? P.h1b : P.h1a;
  float*       h1w = rp ? P.h1a : P.h1b;
  const float* h2r = rp ? P.h2b : P.h2a;
  float*       h2w = rp ? P.h2a : P.h2b;

  if (PHASE==1){
    const float* seg0 = P.tgtT4 + ((size_t)t<<15);
    const float* seg1 = P.attnT4 - 32768;
    const float* seg2 = h1r - 65536;
    mm_core<8,KGW,KF>(seg0, seg1, seg2, smem, zb, lane, wv);
  } else {
    const float* seg0 = h1w;               // h1 NEW (written by K1 this step)
    const float* seg1 = h2r - 32768;       // h2 old
    mm_core<8,KGW,KF>(seg0, seg1, seg1, smem, zb, lane, wv);
  }
  __syncthreads();
  {
    const int gc = tid>>6, b = tid&63;
    float s = 0.f;
    #pragma unroll
    for (int w=0; w<8; ++w) s += zb[(w*8+gc)*64 + b];
    zs[gc*64 + b] = s;
  }
  __syncthreads();
  if (tid < 128){
    const int b = tid&63, j = tid>>6;
    const int h = (wg<<1)+j;
    const float* bias = (PHASE==1) ? P.b1 : P.b2;
    float z[4];
    #pragma unroll
    for (int g=0; g<4; ++g) z[g] = zs[(g*2+j)*64 + b] + bias[(g<<9)+h];
    float* cb = (PHASE==1) ? P.c1 : P.c2;
    float* hw = (PHASE==1) ? h1w  : h2w;
    const int ci = (b<<9)+h;
    float co = cb[ci];
    float cn = sigmf(z[1])*co + sigmf(z[0])*tanhf(z[2]);   // i,f,j,o
    float hn = sigmf(z[3])*tanhf(cn);
    cb[ci] = cn;
    hw[((h>>2)<<8) + (b<<2) + (h&3)] = hn;
  }
}

// ======== K3: q cols {4wg..4wg+3} = h2@Wm^T; eh2 cols {2wg,2wg+1} ========
__global__ __launch_bounds__(512, 2)
void k_qproj(Params P, int rp){
  __shared__ float smem[2048 + 1024 + 3072];
  float* wm = smem;              // 4 x 512
  float* wa = smem + 2048;       // 2 x 512 (k<512 slice of WaT rows)
  float* zb = smem + 3072;       // 8 waves x 6 cols x 64
  const int wg=blockIdx.x, tid=threadIdx.x, lane=tid&63, wv=tid>>6;
  {   // stage Wm: 4 rows x 128 quads = 512 quads, one per thread
    const int c = tid>>7, qi = tid&127;
    const f32x4* src = (const f32x4*)(P.Wm + (size_t)((wg<<2)+c)*512);
    ((f32x4*)wm)[tid] = src[qi];
  }
  if (tid < 256){  // stage Wa k<512 slice: 2 rows x 128 quads
    const int c = tid>>7, qi = tid&127;
    const f32x4* src = (const f32x4*)(P.WaT + (size_t)((wg<<1)+c)*1536);
    ((f32x4*)wa)[tid] = src[qi];
  }
  __syncthreads();
  const float* h2n = rp ? P.h2a : P.h2b;
  float accq[4] = {0.f,0.f,0.f,0.f};
  float acce[2] = {0.f,0.f};
  const int kg0 = wv*16;
  #pragma unroll 4
  for (int i=0;i<16;++i){
    const int kg = kg0 + i;
    f32x4 a = *(const f32x4*)(h2n + ((size_t)kg<<8) + (lane<<2));
    #pragma unroll
    for (int c=0;c<4;++c){
      f32x4 w = *(const f32x4*)(wm + c*512 + (kg<<2));
      accq[c] = fmaf(a[0],w[0],accq[c]); accq[c] = fmaf(a[1],w[1],accq[c]);
      accq[c] = fmaf(a[2],w[2],accq[c]); accq[c] = fmaf(a[3],w[3],accq[c]);
    }
    #pragma unroll
    for (int c=0;c<2;++c){
      f32x4 w = *(const f32x4*)(wa + c*512 + (kg<<2));
      acce[c] = fmaf(a[0],w[0],acce[c]); acce[c] = fmaf(a[1],w[1],acce[c]);
      acce[c] = fmaf(a[2],w[2],acce[c]); acce[c] = fmaf(a[3],w[3],acce[c]);
    }
  }
  #pragma unroll
  for (int c=0;c<4;++c) zb[(wv*6+c)*64 + lane] = accq[c];
  #pragma unroll
  for (int c=0;c<2;++c) zb[(wv*6+4+c)*64 + lane] = acce[c];
  __syncthreads();
  if (tid < 384){
    const int b = tid&63, gc = tid>>6;   // gc in [0,6)
    float s = 0.f;
    #pragma unroll
    for (int w=0; w<8; ++w) s += zb[(w*6+gc)*64 + b];
    if (gc < 4) P.q[(b<<10) + (wg<<2) + gc] = s;
    else        P.eh2[(b<<9) + (wg<<1) + (gc-4)] = s;
  }
}

// -------- enc row fragment (16 floats/lane) --------
struct Row { f32x4 v[4]; };
__device__ __forceinline__ Row load_row(const float* ep, int r){
  Row c;
  const float* p = ep + ((size_t)r<<10);
  c.v[0]=*(const f32x4*)p;     c.v[1]=*(const f32x4*)(p+4);
  c.v[2]=*(const f32x4*)(p+8); c.v[3]=*(const f32x4*)(p+12);
  return c;
}

// ======== K4: attention partials (grid 512 = b x 8 s-groups, 512 thr) ========
__global__ __launch_bounds__(512, 4)
void k_attn(Params P, int rp){
  __shared__ float cpart[4*1024];
  __shared__ float ml[16];
  const int wg=blockIdx.x, tid=threadIdx.x, lane=tid&63, wv=tid>>6;
  const int b = wg>>3, sg = wg&7;
  const int s0 = (sg<<6) + (wv<<3);               // 8 s-rows per wave
  const float* ep = P.enc + (((size_t)b*512 + s0)<<10) + (lane<<4);
  const uint32_t pk = P.pktab[(size_t)wg*8 + wv]; // precomputed (one-time prep)
  const int    nact = P.natab[(size_t)wg*8 + wv];
  const float* qp = P.q + (b<<10) + (lane<<4);
  f32x4 qv0=*(const f32x4*)qp,     qv1=*(const f32x4*)(qp+4),
        qv2=*(const f32x4*)(qp+8), qv3=*(const f32x4*)(qp+12);
  float m=-1e30f, l=0.f;
  f32x4 cx0={0,0,0,0}, cx1={0,0,0,0}, cx2={0,0,0,0}, cx3={0,0,0,0};
  Row r0, r1;
  if (nact > 0) r0 = load_row(ep, (int)(pk & 15));
  if (nact > 1) r1 = load_row(ep, (int)((pk>>4) & 15));
  #pragma clang loop unroll(disable)
  for (int i=0;i<nact;++i){
    Row cur = r0;
    r0 = r1;
    if (i+2 < nact) r1 = load_row(ep, (int)((pk>>(4*(i+2)))&15));
    float d=0.f;
    #pragma unroll
    for (int j=0;j<4;++j){
      d=fmaf(cur.v[0][j],qv0[j],d); d=fmaf(cur.v[1][j],qv1[j],d);
      d=fmaf(cur.v[2][j],qv2[j],d); d=fmaf(cur.v[3][j],qv3[j],d);
    }
    d += __shfl_xor(d,1,64);  d += __shfl_xor(d,2,64);  d += __shfl_xor(d,4,64);
    d += __shfl_xor(d,8,64);  d += __shfl_xor(d,16,64); d += __shfl_xor(d,32,64);
    float mn = fmaxf(m, d);
    float fs = __expf(m - mn), e_ = __expf(d - mn);
    l = l*fs + e_;
    cx0 = cx0*fs + cur.v[0]*e_;  cx1 = cx1*fs + cur.v[1]*e_;
    cx2 = cx2*fs + cur.v[2]*e_;  cx3 = cx3*fs + cur.v[3]*e_;
    m = mn;
  }
  if (wv < 4){
    float* cp = cpart + (wv<<10) + (lane<<2);
    *(f32x4*)(cp      ) = cx0; *(f32x4*)(cp + 256) = cx1;
    *(f32x4*)(cp + 512) = cx2; *(f32x4*)(cp + 768) = cx3;
  }
  if (lane==0){ ml[wv*2]=m; ml[wv*2+1]=l; }
  __syncthreads();
  if (wv >= 4){
    float M = -1e30f;
    #pragma unroll
    for (int w=0;w<8;++w) M = fmaxf(M, ml[w*2]);
    const float ewj = __expf(ml[(wv-4)*2]-M);
    const float ewo = __expf(ml[wv*2]-M);
    float* cp = cpart + ((wv-4)<<10) + (lane<<2);
    f32x4 q0=*(f32x4*)(cp), q1=*(f32x4*)(cp+256), q2=*(f32x4*)(cp+512), q3=*(f32x4*)(cp+768);
    q0 = q0*ewj + cx0*ewo;  q1 = q1*ewj + cx1*ewo;
    q2 = q2*ewj + cx2*ewo;  q3 = q3*ewj + cx3*ewo;
    *(f32x4*)(cp) = q0; *(f32x4*)(cp+256)=q1; *(f32x4*)(cp+512)=q2; *(f32x4*)(cp+768)=q3;
    if (wv==4 && lane==0){
      float L = 0.f;
      #pragma unroll
      for (int w=0;w<8;++w) L += __expf(ml[w*2]-M)*ml[w*2+1];
      P.part_ml[b*16 + sg*2]   = M;
      P.part_ml[b*16 + sg*2+1] = L;
    }
  }
  __syncthreads();
  #pragma unroll
  for (int h=0; h<2; ++h){
    const int f = tid + (h<<9);
    const int fidx = (((f&15)>>2)<<8) + ((f>>4)<<2) + (f&3);
    float c = 0.f;
    #pragma unroll
    for (int p=0;p<4;++p) c += cpart[(p<<10) + fidx];
    P.part_ctx[((size_t)sg<<16) + ((f>>2)<<8) + (b<<2) + (f&3)] = c;
  }
}

// ======== K5: attn = eh2 + ctx @ Wa[512:1536] (grid 256; 2 cols/WG) ========
__global__ __launch_bounds__(512, 2)
void k_out(Params P, int t, int rp){
  __shared__ float smem[2048 + 1024];
  float* wa = smem;              // 2 x 1024 (Wa rows, k slice [512:1536))
  float* zb = smem + 2048;
  const int wg=blockIdx.x, tid=threadIdx.x, lane=tid&63, wv=tid>>6;
  {   // stage 2 rows x 256 quads = 512 quads, one per thread
    const int c = tid>>8, qi = tid&255;
    const f32x4* src = (const f32x4*)(P.WaT + (size_t)((wg<<1)+c)*1536 + 512);
    ((f32x4*)wa)[tid] = src[qi];
  }
  __syncthreads();
  // per-lane (b = lane) 8-way softmax combine weights
  f32x4 mlv0 = *(const f32x4*)(P.part_ml + lane*16);
  f32x4 mlv1 = *(const f32x4*)(P.part_ml + lane*16 + 4);
  f32x4 mlv2 = *(const f32x4*)(P.part_ml + lane*16 + 8);
  f32x4 mlv3 = *(const f32x4*)(P.part_ml + lane*16 + 12);
  float Ms[8] = {mlv0[0],mlv0[2],mlv1[0],mlv1[2],mlv2[0],mlv2[2],mlv3[0],mlv3[2]};
  float Ls[8] = {mlv0[1],mlv0[3],mlv1[1],mlv1[3],mlv2[1],mlv2[3],mlv3[1],mlv3[3]};
  float M = -1e30f;
  #pragma unroll
  for (int s=0;s<8;++s) M = fmaxf(M, Ms[s]);
  float ws[8]; float L = 0.f;
  #pragma unroll
  for (int s=0;s<8;++s){ ws[s] = __expf(Ms[s]-M); L += ws[s]*Ls[s]; }
  float inv = 1.f/L;
  #pragma unroll
  for (int s=0;s<8;++s) ws[s] *= inv;

  float acc0=0.f, acc1=0.f;
  const int kk0 = wv*32;
  #pragma unroll 2
  for (int i=0;i<32;++i){
    const int kk = kk0 + i;                       // [0,256) -> ctx feature quad
    const float* pc = P.part_ctx + ((size_t)kk<<8) + (lane<<2);
    f32x4 a = {0.f,0.f,0.f,0.f};
    #pragma unroll
    for (int s=0;s<8;++s){
      f32x4 g = *(const f32x4*)(pc + (size_t)s*65536);
      a[0] = fmaf(ws[s],g[0],a[0]); a[1] = fmaf(ws[s],g[1],a[1]);
      a[2] = fmaf(ws[s],g[2],a[2]); a[3] = fmaf(ws[s],g[3],a[3]);
    }
    f32x4 u0 = *(const f32x4*)(wa + (kk<<2));
    f32x4 u1 = *(const f32x4*)(wa + 1024 + (kk<<2));
    acc0 = fmaf(a[0],u0[0],acc0); acc0 = fmaf(a[1],u0[1],acc0);
    acc0 = fmaf(a[2],u0[2],acc0); acc0 = fmaf(a[3],u0[3],acc0);
    acc1 = fmaf(a[0],u1[0],acc1); acc1 = fmaf(a[1],u1[1],acc1);
    acc1 = fmaf(a[2],u1[2],acc1); acc1 = fmaf(a[3],u1[3],acc1);
  }
  zb[(wv*2+0)*64 + lane] = acc0;
  zb[(wv*2+1)*64 + lane] = acc1;
  __syncthreads();
  if (tid < 128){
    const int b = tid&63, j = tid>>6;
    const int n = (wg<<1)+j;
    float s = P.eh2[(b<<9) + n];
    #pragma unroll
    for (int w=0;w<8;++w) s += zb[(w*2+j)*64 + b];
    P.out[(((size_t)b<<8) + t)*512 + n] = s;
    P.attnT4[((n>>2)<<8) + (b<<2) + (n&3)] = s;
  }
}

// ======== prep kernels ========
__global__ void transT(const float* a, const float* bsrc, float* dst, int K, int N, int KA){
  __shared__ float tile[32][33];
  const int ntk = K>>5;
  const int tn = blockIdx.x / ntk, tk = blockIdx.x - tn*ntk;
  const int tid = threadIdx.x;
  const int c = tid & 31, r = tid >> 5;
  for (int rr=r; rr<32; rr+=8){
    const int k = (tk<<5)+rr, n = (tn<<5)+c;
    tile[rr][c] = (k<KA) ? a[(size_t)k*N+n] : bsrc[(size_t)(k-KA)*N+n];
  }
  __syncthreads();
  for (int rr=r; rr<32; rr+=8){
    const int n = (tn<<5)+rr, k = (tk<<5)+c;
    dst[(size_t)n*K + k] = tile[c][rr];
  }
}

// tgt[b][t][k] -> tgtT4[t][k>>2][b][k&3]
__global__ void prep_tgt(const float* tgt, float* tgtT4){
  __shared__ float xt[64*517];
  const int t = blockIdx.x, tid = threadIdx.x;   // 256 threads
  for (int i=tid; i<64*512; i+=256){
    const int bb = i>>9, k = i&511;
    xt[bb*517 + k] = tgt[((size_t)bb*256 + t)*512 + k];
  }
  __syncthreads();
  for (int i=tid; i<128*64; i+=256){
    const int kg = i>>6, bb = i&63;
    f32x4 v = { xt[bb*517 + kg*4], xt[bb*517 + kg*4 + 1],
                xt[bb*517 + kg*4 + 2], xt[bb*517 + kg*4 + 3] };
    *(f32x4*)(tgtT4 + ((size_t)t<<15) + (kg<<8) + (bb<<2)) = v;
  }
}

// one-time: per-wave packed unmasked-row lists (64 b x 8 sg x 8 wv, 8 rows ea)
__global__ void prep_pk(const float* mask, uint32_t* pktab, int* natab){
  const int e = blockIdx.x*blockDim.x + threadIdx.x;   // 4096 entries
  if (e >= 4096) return;
  const int wv = e & 7, sg = (e>>3) & 7, b = e>>6;
  const int s0 = (sg<<6) + (wv<<3);
  uint32_t pk = 0; int nact = 0;
  for (int r=0;r<8;++r){
    if (mask[(b<<9) + s0 + r] == 0.f){ pk |= (uint32_t)r << (4*nact); ++nact; }
  }
  pktab[((size_t)(b*8+sg))*8 + wv] = pk;
  natab[((size_t)(b*8+sg))*8 + wv] = nact;
}

__global__ void init_state(const float* fwh, const float* fwc, const float* bwh, const float* bwc,
                           float* h1a, float* h2a, float* attnT4, float* c1, float* c2){
  const int i = blockIdx.x*blockDim.x + threadIdx.x;
  if (i < 64*512){
    const int bb = i>>9, k = i&511;
    const int t4 = ((k>>2)<<8) + (bb<<2) + (k&3);
    h1a[t4] = fwh[i];
    h2a[t4] = bwh[i];
    attnT4[t4] = 0.f;
    c1[i] = fwc[i];
    c2[i] = bwc[i];
  }
}

extern "C" void kernel_launch(void* const* d_in, const int* in_sizes, int n_in,
                              void* d_out, int out_size, void* d_ws, size_t ws_size,
                              hipStream_t stream){
  if (n_in < 15) return;
  const float* tgt = (const float*)d_in[0];
  const float* fwh = (const float*)d_in[1];
  const float* fwc = (const float*)d_in[2];
  const float* bwh = (const float*)d_in[3];
  const float* bwc = (const float*)d_in[4];
  const float* enc = (const float*)d_in[5];
  const float* msk = (const float*)d_in[6];
  const float* Wm  = (const float*)d_in[7];
  const float* Wa  = (const float*)d_in[8];
  const float* ki1 = (const float*)d_in[9];
  const float* kr1 = (const float*)d_in[10];
  const float* b1  = (const float*)d_in[11];
  const float* ki2 = (const float*)d_in[12];
  const float* kr2 = (const float*)d_in[13];
  const float* b2  = (const float*)d_in[14];

  char* w = (char*)d_ws;
  size_t o = 0;
  auto carve = [&](size_t bytes)->char*{
    char* r = w + o; o = (o + bytes + 255) & ~(size_t)255; return r;
  };
  float* W1T    = (float*)carve(2048ull*1536*4);
  float* W2T    = (float*)carve(2048ull*1024*4);
  float* WaT    = (float*)carve(512ull*1536*4);
  float* tgtT4  = (float*)carve(256ull*128*256*4);
  float* h1a    = (float*)carve(128ull*256*4);
  float* h1b    = (float*)carve(128ull*256*4);
  float* h2a    = (float*)carve(128ull*256*4);
  float* h2b    = (float*)carve(128ull*256*4);
  float* attnT4 = (float*)carve(128ull*256*4);
  float* q      = (float*)carve(64ull*1024*4);
  float* c1     = (float*)carve(64ull*512*4);
  float* c2     = (float*)carve(64ull*512*4);
  float* eh2    = (float*)carve(64ull*512*4);
  float* part_ctx = (float*)carve(8ull*256*256*4);
  float* part_ml  = (float*)carve(64ull*16*4);
  uint32_t* pktab = (uint32_t*)carve(4096ull*4);
  int*      natab = (int*)carve(4096ull*4);
  if (o > ws_size) return;   // ~63 MB needed

  hipLaunchKernelGGL(transT, dim3(64*48), dim3(256), 0, stream, ki1, kr1, W1T, 1536, 2048, 1024);
  hipLaunchKernelGGL(transT, dim3(64*32), dim3(256), 0, stream, ki2, kr2, W2T, 1024, 2048, 512);
  hipLaunchKernelGGL(transT, dim3(16*48), dim3(256), 0, stream, Wa,  Wa,  WaT, 1536, 512, 1536);
  hipLaunchKernelGGL(prep_tgt, dim3(256), dim3(256), 0, stream, tgt, tgtT4);
  hipLaunchKernelGGL(prep_pk,  dim3(16),  dim3(256), 0, stream, msk, pktab, natab);
  hipLaunchKernelGGL(init_state, dim3(128), dim3(256), 0, stream,
                     fwh, fwc, bwh, bwc, h1a, h2a, attnT4, c1, c2);

  Params P;
  P.tgtT4 = tgtT4; P.mask = msk; P.b1 = b1; P.b2 = b2;
  P.Wm = Wm; P.enc = enc;
  P.W1T = W1T; P.W2T = W2T; P.WaT = WaT;
  P.h1a = h1a; P.h1b = h1b; P.h2a = h2a; P.h2b = h2b;
  P.attnT4 = attnT4; P.q = q;
  P.c1 = c1; P.c2 = c2; P.eh2 = eh2;
  P.part_ctx = part_ctx; P.part_ml = part_ml;
  P.pktab = pktab; P.natab = natab;
  P.out = (float*)d_out;

  for (int t = 0; t < 256; ++t){
    const int rp = t & 1;
    hipLaunchKernelGGL(k_lstm<1>, dim3(256), dim3(512), 0, stream, P, t, rp);
    hipLaunchKernelGGL(k_lstm<2>, dim3(256), dim3(512), 0, stream, P, t, rp);
    hipLaunchKernelGGL(k_qproj,   dim3(256), dim3(512), 0, stream, P, rp);
    hipLaunchKernelGGL(k_attn,    dim3(512), dim3(512), 0, stream, P, rp);
    hipLaunchKernelGGL(k_out,     dim3(256), dim3(512), 0, stream, P, t, rp);
  }
}

// Round 17
// 18063.387 us; speedup vs baseline: 1.2833x; 1.2833x over previous
//
#include <hip/hip_runtime.h>
#include <stdint.h>

// Seq2Seq decoder (2-layer LSTM + Luong attention), B=64, T=256, S=512, H=512.
// Round 17: exact R15 revert (best: 18.38ms) + 2-deep row prefetch in k_attn
// (the only R16 piece that doesn't change work decomposition).
// R16 lesson: grid-512 k_attn halved per-wave work but kept per-WG fixed costs
// -> overhead grew faster than latency hiding helped (-26%). Fat WGs win.
// All-f32 datapath (chaos: 2^-23 noise amplifies ~1e5x; bf16 impossible).

typedef float f32x4 __attribute__((ext_vector_type(4)));

struct Params {
  const float* tgtT4;   // [256][128][64][4]
  const float* mask;    // [64][512] (1.0 = masked)
  const float* b1;      // [2048]
  const float* b2;      // [2048]
  const float* Wm;      // [1024][512] raw (row n = weights for q col n)
  const float* enc;     // [64][512][1024]
  const float* W1T;     // [2048][1536]
  const float* W2T;     // [2048][1024]
  const float* WaT;     // [512][1536]
  float *h1a,*h1b,*h2a,*h2b;   // T4 [128][64][4]
  float *attnT4;               // T4 [128][64][4]
  float *q;                    // [64][1024]
  float *c1,*c2;               // [64][512]
  float *eh2;                  // [64][512]
  float *part_ctx;             // [4][256][64][4]
  float *part_ml;              // [64][4][2]
  uint64_t *pktab;             // [64][4][8] packed unmasked-row lists
  int      *natab;             // [64][4][8] active counts
  float *out;                  // [64][256][512]
};

__device__ __forceinline__ float sigmf(float x){ return 1.f/(1.f+__expf(-x)); }

// -------- GEMM core: out[c][b] += sum_k act[k][b] * wL[c][k] --------
template<int NCOLS, int KGW, int KST>
__device__ __forceinline__ void mm_core(const float* seg0, const float* seg1, const float* seg2,
                                        const float* wL, float* zb, int lane, int wv){
  float acc[NCOLS];
  #pragma unroll
  for (int c=0;c<NCOLS;++c) acc[c]=0.f;
  const int kg0 = wv*KGW;
  #pragma unroll 4
  for (int i=0;i<KGW;++i){
    const int kg = kg0 + i;
    const float* bp = (kg<128) ? seg0 : ((kg<256) ? seg1 : seg2);
    f32x4 a = *(const f32x4*)(bp + ((size_t)kg<<8) + (lane<<2));
    #pragma unroll
    for (int c=0;c<NCOLS;++c){
      f32x4 w = *(const f32x4*)(wL + c*KST + (kg<<2));
      acc[c] = fmaf(a[0],w[0],acc[c]); acc[c] = fmaf(a[1],w[1],acc[c]);
      acc[c] = fmaf(a[2],w[2],acc[c]); acc[c] = fmaf(a[3],w[3],acc[c]);
    }
  }
  #pragma unroll
  for (int c=0;c<NCOLS;++c) zb[(wv*NCOLS+c)*64 + lane] = acc[c];
}

// ======== K1/K2: LSTM layers (grid 256, 512 thr; WG owns 2 h-cols) ========
template<int PHASE>
__global__ __launch_bounds__(512, 2)
void k_lstm(Params P, int t, int rp){
  constexpr int KF  = (PHASE==1) ? 1536 : 1024;
  constexpr int KGW = (PHASE==1) ? 48 : 32;
  constexpr int KQ  = KF/4;
  __shared__ float smem[8*KF + 4096 + 512];
  float* zb = smem + 8*KF;
  float* zs = zb + 4096;
  const int wg=blockIdx.x, tid=threadIdx.x, lane=tid&63, wv=tid>>6;
  const float* WT = (PHASE==1) ? P.W1T : P.W2T;
  #pragma unroll
  for (int c=0;c<8;++c){
    const int n = ((c>>1)<<9) + (wg<<1) + (c&1);
    const f32x4* src = (const f32x4*)(WT + (size_t)n*KF);
    f32x4* dst = (f32x4*)(smem + c*KF);
    if (tid < KQ) dst[tid] = src[tid];
  }
  __syncthreads();

  const float* h1r = rp ? P.h1b : P.h1a;
  float*       h1w = rp ? P.h1a : P.h1b;
  const float* h2r = rp ? P.h2b : P.h2a;
  float*       h2w = rp ? P.h2a : P.h2b;

  if (PHASE==1){
    const float* seg0 = P.tgtT4 + ((size_t)t<<15);
    const float* seg1 = P.attnT4 - 32768;
    const float* seg2 = h1r - 65536;
    mm_core<8,KGW,KF>(seg0, seg1, seg2, smem, zb, lane, wv);
  } else {
    const float* seg0 = h1w;               // h1 NEW (written by K1 this step)
    const float* seg1 = h2r - 32768;       // h2 old
    mm_core<8,KGW,KF>(seg0, seg1, seg1, smem, zb, lane, wv);
  }
  __syncthreads();
  {
    const int gc = tid>>6, b = tid&63;
    float s = 0.f;
    #pragma unroll
    for (int w=0; w<8; ++w) s += zb[(w*8+gc)*64 + b];
    zs[gc*64 + b] = s;
  }
  __syncthreads();
  if (tid < 128){
    const int b = tid&63, j = tid>>6;
    const int h = (wg<<1)+j;
    const float* bias = (PHASE==1) ? P.b1 : P.b2;
    float z[4];
    #pragma unroll
    for (int g=0; g<4; ++g) z[g] = zs[(g*2+j)*64 + b] + bias[(g<<9)+h];
    float* cb = (PHASE==1) ? P.c1 : P.c2;
    float* hw = (PHASE==1) ? h1w  : h2w;
    const int ci = (b<<9)+h;
    float co = cb[ci];
    float cn = sigmf(z[1])*co + sigmf(z[0])*tanhf(z[2]);   // i,f,j,o
    float hn = sigmf(z[3])*tanhf(cn);
    cb[ci] = cn;
    hw[((h>>2)<<8) + (b<<2) + (h&3)] = hn;
  }
}

// ======== K3: q cols {4wg..4wg+3} = h2@Wm^T; eh2 cols {2wg,2wg+1} ========
__global__ __launch_bounds__(512, 2)
void k_qproj(Params P, int rp){
  __shared__ float smem[2048 + 1024 + 3072];
  float* wm = smem;              // 4 x 512
  float* wa = smem + 2048;       // 2 x 512 (k<512 slice of WaT rows)
  float* zb = smem + 3072;       // 8 waves x 6 cols x 64
  const int wg=blockIdx.x, tid=threadIdx.x, lane=tid&63, wv=tid>>6;
  {   // stage Wm: 4 rows x 128 quads = 512 quads, one per thread
    const int c = tid>>7, qi = tid&127;
    const f32x4* src = (const f32x4*)(P.Wm + (size_t)((wg<<2)+c)*512);
    ((f32x4*)wm)[tid] = src[qi];
  }
  if (tid < 256){  // stage Wa k<512 slice: 2 rows x 128 quads
    const int c = tid>>7, qi = tid&127;
    const f32x4* src = (const f32x4*)(P.WaT + (size_t)((wg<<1)+c)*1536);
    ((f32x4*)wa)[tid] = src[qi];
  }
  __syncthreads();
  const float* h2n = rp ? P.h2a : P.h2b;
  float accq[4] = {0.f,0.f,0.f,0.f};
  float acce[2] = {0.f,0.f};
  const int kg0 = wv*16;
  #pragma unroll 4
  for (int i=0;i<16;++i){
    const int kg = kg0 + i;
    f32x4 a = *(const f32x4*)(h2n + ((size_t)kg<<8) + (lane<<2));
    #pragma unroll
    for (int c=0;c<4;++c){
      f32x4 w = *(const f32x4*)(wm + c*512 + (kg<<2));
      accq[c] = fmaf(a[0],w[0],accq[c]); accq[c] = fmaf(a[1],w[1],accq[c]);
      accq[c] = fmaf(a[2],w[2],accq[c]); accq[c] = fmaf(a[3],w[3],accq[c]);
    }
    #pragma unroll
    for (int c=0;c<2;++c){
      f32x4 w = *(const f32x4*)(wa + c*512 + (kg<<2));
      acce[c] = fmaf(a[0],w[0],acce[c]); acce[c] = fmaf(a[1],w[1],acce[c]);
      acce[c] = fmaf(a[2],w[2],acce[c]); acce[c] = fmaf(a[3],w[3],acce[c]);
    }
  }
  #pragma unroll
  for (int c=0;c<4;++c) zb[(wv*6+c)*64 + lane] = accq[c];
  #pragma unroll
  for (int c=0;c<2;++c) zb[(wv*6+4+c)*64 + lane] = acce[c];
  __syncthreads();
  if (tid < 384){
    const int b = tid&63, gc = tid>>6;   // gc in [0,6)
    float s = 0.f;
    #pragma unroll
    for (int w=0; w<8; ++w) s += zb[(w*6+gc)*64 + b];
    if (gc < 4) P.q[(b<<10) + (wg<<2) + gc] = s;
    else        P.eh2[(b<<9) + (wg<<1) + (gc-4)] = s;
  }
}

// -------- enc row fragment (16 floats/lane) --------
struct Row { f32x4 v[4]; };
__device__ __forceinline__ Row load_row(const float* ep, int r){
  Row c;
  const float* p = ep + ((size_t)r<<10);
  c.v[0]=*(const f32x4*)p;     c.v[1]=*(const f32x4*)(p+4);
  c.v[2]=*(const f32x4*)(p+8); c.v[3]=*(const f32x4*)(p+12);
  return c;
}

// ======== K4: attention partials (grid 256 = b x 4 s-groups, 512 thr) ========
__global__ __launch_bounds__(512, 2)
void k_attn(Params P, int rp){
  __shared__ float cpart[4*1024];
  __shared__ float ml[16];
  const int wg=blockIdx.x, tid=threadIdx.x, lane=tid&63, wv=tid>>6;
  const int b = wg>>2, sg = wg&3;
  const int s0 = (sg<<7) + (wv<<4);               // 16 s-rows per wave
  const float* ep = P.enc + (((size_t)b*512 + s0)<<10) + (lane<<4);
  const uint64_t pk = P.pktab[(size_t)wg*8 + wv]; // precomputed (one-time prep)
  const int    nact = P.natab[(size_t)wg*8 + wv];
  const float* qp = P.q + (b<<10) + (lane<<4);
  f32x4 qv0=*(const f32x4*)qp,     qv1=*(const f32x4*)(qp+4),
        qv2=*(const f32x4*)(qp+8), qv3=*(const f32x4*)(qp+12);
  float m=-1e30f, l=0.f;
  f32x4 cx0={0,0,0,0}, cx1={0,0,0,0}, cx2={0,0,0,0}, cx3={0,0,0,0};
  Row r0, r1;
  if (nact > 0) r0 = load_row(ep, (int)(pk & 15));
  if (nact > 1) r1 = load_row(ep, (int)((pk>>4) & 15));
  #pragma clang loop unroll(disable)
  for (int i=0;i<nact;++i){
    Row cur = r0;
    r0 = r1;
    if (i+2 < nact) r1 = load_row(ep, (int)((pk>>(4*(i+2)))&15));
    float d=0.f;
    #pragma unroll
    for (int j=0;j<4;++j){
      d=fmaf(cur.v[0][j],qv0[j],d); d=fmaf(cur.v[1][j],qv1[j],d);
      d=fmaf(cur.v[2][j],qv2[j],d); d=fmaf(cur.v[3][j],qv3[j],d);
    }
    d += __shfl_xor(d,1,64);  d += __shfl_xor(d,2,64);  d += __shfl_xor(d,4,64);
    d += __shfl_xor(d,8,64);  d += __shfl_xor(d,16,64); d += __shfl_xor(d,32,64);
    float mn = fmaxf(m, d);
    float fs = __expf(m - mn), e_ = __expf(d - mn);
    l = l*fs + e_;
    cx0 = cx0*fs + cur.v[0]*e_;  cx1 = cx1*fs + cur.v[1]*e_;
    cx2 = cx2*fs + cur.v[2]*e_;  cx3 = cx3*fs + cur.v[3]*e_;
    m = mn;
  }
  if (wv < 4){
    float* cp = cpart + (wv<<10) + (lane<<2);
    *(f32x4*)(cp      ) = cx0; *(f32x4*)(cp + 256) = cx1;
    *(f32x4*)(cp + 512) = cx2; *(f32x4*)(cp + 768) = cx3;
  }
  if (lane==0){ ml[wv*2]=m; ml[wv*2+1]=l; }
  __syncthreads();
  if (wv >= 4){
    float M = -1e30f;
    #pragma unroll
    for (int w=0;w<8;++w) M = fmaxf(M, ml[w*2]);
    const float ewj = __expf(ml[(wv-4)*2]-M);
    const float ewo = __expf(ml[wv*2]-M);
    float* cp = cpart + ((wv-4)<<10) + (lane<<2);
    f32x4 q0=*(f32x4*)(cp), q1=*(f32x4*)(cp+256), q2=*(f32x4*)(cp+512), q3=*(f32x4*)(cp+768);
    q0 = q0*ewj + cx0*ewo;  q1 = q1*ewj + cx1*ewo;
    q2 = q2*ewj + cx2*ewo;  q3 = q3*ewj + cx3*ewo;
    *(f32x4*)(cp) = q0; *(f32x4*)(cp+256)=q1; *(f32x4*)(cp+512)=q2; *(f32x4*)(cp+768)=q3;
    if (wv==4 && lane==0){
      float L = 0.f;
      #pragma unroll
      for (int w=0;w<8;++w) L += __expf(ml[w*2]-M)*ml[w*2+1];
      P.part_ml[b*8 + sg*2]   = M;
      P.part_ml[b*8 + sg*2+1] = L;
    }
  }
  __syncthreads();
  #pragma unroll
  for (int h=0; h<2; ++h){
    const int f = tid + (h<<9);
    const int fidx = (((f&15)>>2)<<8) + ((f>>4)<<2) + (f&3);
    float c = 0.f;
    #pragma unroll
    for (int p=0;p<4;++p) c += cpart[(p<<10) + fidx];
    P.part_ctx[((size_t)sg<<16) + ((f>>2)<<8) + (b<<2) + (f&3)] = c;
  }
}

// ======== K5: attn = eh2 + ctx @ Wa[512:1536] (grid 256; 2 cols/WG) ========
__global__ __launch_bounds__(512, 2)
void k_out(Params P, int t, int rp){
  __shared__ float smem[2048 + 1024];
  float* wa = smem;              // 2 x 1024 (Wa rows, k slice [512:1536))
  float* zb = smem + 2048;
  const int wg=blockIdx.x, tid=threadIdx.x, lane=tid&63, wv=tid>>6;
  {   // stage 2 rows x 256 quads = 512 quads, one per thread
    const int c = tid>>8, qi = tid&255;
    const f32x4* src = (const f32x4*)(P.WaT + (size_t)((wg<<1)+c)*1536 + 512);
    ((f32x4*)wa)[tid] = src[qi];
  }
  __syncthreads();
  // per-lane (b = lane) 4-way softmax combine weights
  f32x4 mlv0 = *(const f32x4*)(P.part_ml + lane*8);
  f32x4 mlv1 = *(const f32x4*)(P.part_ml + lane*8 + 4);
  float M0=mlv0[0], L0=mlv0[1], M1=mlv0[2], L1=mlv0[3];
  float M2=mlv1[0], L2=mlv1[1], M3=mlv1[2], L3=mlv1[3];
  float M = fmaxf(fmaxf(M0,M1), fmaxf(M2,M3));
  float w0=__expf(M0-M), w1=__expf(M1-M), w2=__expf(M2-M), w3=__expf(M3-M);
  float inv = 1.f/(w0*L0 + w1*L1 + w2*L2 + w3*L3);
  w0*=inv; w1*=inv; w2*=inv; w3*=inv;

  float acc0=0.f, acc1=0.f;
  const int kk0 = wv*32;
  #pragma unroll 2
  for (int i=0;i<32;++i){
    const int kk = kk0 + i;                       // [0,256) -> ctx feature quad
    const float* pc = P.part_ctx + ((size_t)kk<<8) + (lane<<2);
    f32x4 g0 = *(const f32x4*)pc;
    f32x4 g1 = *(const f32x4*)(pc + 65536);
    f32x4 g2 = *(const f32x4*)(pc + 131072);
    f32x4 g3 = *(const f32x4*)(pc + 196608);
    f32x4 a;
    #pragma unroll
    for (int j=0;j<4;++j) a[j] = w0*g0[j] + w1*g1[j] + w2*g2[j] + w3*g3[j];
    f32x4 u0 = *(const f32x4*)(wa + (kk<<2));
    f32x4 u1 = *(const f32x4*)(wa + 1024 + (kk<<2));
    acc0 = fmaf(a[0],u0[0],acc0); acc0 = fmaf(a[1],u0[1],acc0);
    acc0 = fmaf(a[2],u0[2],acc0); acc0 = fmaf(a[3],u0[3],acc0);
    acc1 = fmaf(a[0],u1[0],acc1); acc1 = fmaf(a[1],u1[1],acc1);
    acc1 = fmaf(a[2],u1[2],acc1); acc1 = fmaf(a[3],u1[3],acc1);
  }
  zb[(wv*2+0)*64 + lane] = acc0;
  zb[(wv*2+1)*64 + lane] = acc1;
  __syncthreads();
  if (tid < 128){
    const int b = tid&63, j = tid>>6;
    const int n = (wg<<1)+j;
    float s = P.eh2[(b<<9) + n];
    #pragma unroll
    for (int w=0;w<8;++w) s += zb[(w*2+j)*64 + b];
    P.out[(((size_t)b<<8) + t)*512 + n] = s;
    P.attnT4[((n>>2)<<8) + (b<<2) + (n&3)] = s;
  }
}

// ======== prep kernels ========
__global__ void transT(const float* a, const float* bsrc, float* dst, int K, int N, int KA){
  __shared__ float tile[32][33];
  const int ntk = K>>5;
  const int tn = blockIdx.x / ntk, tk = blockIdx.x - tn*ntk;
  const int tid = threadIdx.x;
  const int c = tid & 31, r = tid >> 5;
  for (int rr=r; rr<32; rr+=8){
    const int k = (tk<<5)+rr, n = (tn<<5)+c;
    tile[rr][c] = (k<KA) ? a[(size_t)k*N+n] : bsrc[(size_t)(k-KA)*N+n];
  }
  __syncthreads();
  for (int rr=r; rr<32; rr+=8){
    const int n = (tn<<5)+rr, k = (tk<<5)+c;
    dst[(size_t)n*K + k] = tile[c][rr];
  }
}

// tgt[b][t][k] -> tgtT4[t][k>>2][b][k&3]
__global__ void prep_tgt(const float* tgt, float* tgtT4){
  __shared__ float xt[64*517];
  const int t = blockIdx.x, tid = threadIdx.x;   // 256 threads
  for (int i=tid; i<64*512; i+=256){
    const int bb = i>>9, k = i&511;
    xt[bb*517 + k] = tgt[((size_t)bb*256 + t)*512 + k];
  }
  __syncthreads();
  for (int i=tid; i<128*64; i+=256){
    const int kg = i>>6, bb = i&63;
    f32x4 v = { xt[bb*517 + kg*4], xt[bb*517 + kg*4 + 1],
                xt[bb*517 + kg*4 + 2], xt[bb*517 + kg*4 + 3] };
    *(f32x4*)(tgtT4 + ((size_t)t<<15) + (kg<<8) + (bb<<2)) = v;
  }
}

// one-time: per-wave packed unmasked-row lists (64 b x 4 sg x 8 wv)
__global__ void prep_pk(const float* mask, uint64_t* pktab, int* natab){
  const int e = blockIdx.x*blockDim.x + threadIdx.x;   // 2048 entries
  if (e >= 2048) return;
  const int wv = e & 7, sg = (e>>3) & 3, b = e>>5;
  const int s0 = (sg<<7) + (wv<<4);
  uint64_t pk = 0; int nact = 0;
  for (int r=0;r<16;++r){
    if (mask[(b<<9) + s0 + r] == 0.f){ pk |= (uint64_t)r << (4*nact); ++nact; }
  }
  pktab[((size_t)(b*4+sg))*8 + wv] = pk;
  natab[((size_t)(b*4+sg))*8 + wv] = nact;
}

__global__ void init_state(const float* fwh, const float* fwc, const float* bwh, const float* bwc,
                           float* h1a, float* h2a, float* attnT4, float* c1, float* c2){
  const int i = blockIdx.x*blockDim.x + threadIdx.x;
  if (i < 64*512){
    const int bb = i>>9, k = i&511;
    const int t4 = ((k>>2)<<8) + (bb<<2) + (k&3);
    h1a[t4] = fwh[i];
    h2a[t4] = bwh[i];
    attnT4[t4] = 0.f;
    c1[i] = fwc[i];
    c2[i] = bwc[i];
  }
}

extern "C" void kernel_launch(void* const* d_in, const int* in_sizes, int n_in,
                              void* d_out, int out_size, void* d_ws, size_t ws_size,
                              hipStream_t stream){
  if (n_in < 15) return;
  const float* tgt = (const float*)d_in[0];
  const float* fwh = (const float*)d_in[1];
  const float* fwc = (const float*)d_in[2];
  const float* bwh = (const float*)d_in[3];
  const float* bwc = (const float*)d_in[4];
  const float* enc = (const float*)d_in[5];
  const float* msk = (const float*)d_in[6];
  const float* Wm  = (const float*)d_in[7];
  const float* Wa  = (const float*)d_in[8];
  const float* ki1 = (const float*)d_in[9];
  const float* kr1 = (const float*)d_in[10];
  const float* b1  = (const float*)d_in[11];
  const float* ki2 = (const float*)d_in[12];
  const float* kr2 = (const float*)d_in[13];
  const float* b2  = (const float*)d_in[14];

  char* w = (char*)d_ws;
  size_t o = 0;
  auto carve = [&](size_t bytes)->char*{
    char* r = w + o; o = (o + bytes + 255) & ~(size_t)255; return r;
  };
  float* W1T    = (float*)carve(2048ull*1536*4);
  float* W2T    = (float*)carve(2048ull*1024*4);
  float* WaT    = (float*)carve(512ull*1536*4);
  float* tgtT4  = (float*)carve(256ull*128*256*4);
  float* h1a    = (float*)carve(128ull*256*4);
  float* h1b    = (float*)carve(128ull*256*4);
  float* h2a    = (float*)carve(128ull*256*4);
  float* h2b    = (float*)carve(128ull*256*4);
  float* attnT4 = (float*)carve(128ull*256*4);
  float* q      = (float*)carve(64ull*1024*4);
  float* c1     = (float*)carve(64ull*512*4);
  float* c2     = (float*)carve(64ull*512*4);
  float* eh2    = (float*)carve(64ull*512*4);
  float* part_ctx = (float*)carve(4ull*256*256*4);
  float* part_ml  = (float*)carve(64ull*8*4);
  uint64_t* pktab = (uint64_t*)carve(2048ull*8);
  int*      natab = (int*)carve(2048ull*4);
  if (o > ws_size) return;   // ~62 MB needed

  hipLaunchKernelGGL(transT, dim3(64*48), dim3(256), 0, stream, ki1, kr1, W1T, 1536, 2048, 1024);
  hipLaunchKernelGGL(transT, dim3(64*32), dim3(256), 0, stream, ki2, kr2, W2T, 1024, 2048, 512);
  hipLaunchKernelGGL(transT, dim3(16*48), dim3(256), 0, stream, Wa,  Wa,  WaT, 1536, 512, 1536);
  hipLaunchKernelGGL(prep_tgt, dim3(256), dim3(256), 0, stream, tgt, tgtT4);
  hipLaunchKernelGGL(prep_pk,  dim3(8),   dim3(256), 0, stream, msk, pktab, natab);
  hipLaunchKernelGGL(init_state, dim3(128), dim3(256), 0, stream,
                     fwh, fwc, bwh, bwc, h1a, h2a, attnT4, c1, c2);

  Params P;
  P.tgtT4 = tgtT4; P.mask = msk; P.b1 = b1; P.b2 = b2;
  P.Wm = Wm; P.enc = enc;
  P.W1T = W1T; P.W2T = W2T; P.WaT = WaT;
  P.h1a = h1a; P.h1b = h1b; P.h2a = h2a; P.h2b = h2b;
  P.attnT4 = attnT4; P.q = q;
  P.c1 = c1; P.c2 = c2; P.eh2 = eh2;
  P.part_ctx = part_ctx; P.part_ml = part_ml;
  P.pktab = pktab; P.natab = natab;
  P.out = (float*)d_out;

  for (int t = 0; t < 256; ++t){
    const int rp = t & 1;
    hipLaunchKernelGGL(k_lstm<1>, dim3(256), dim3(512), 0, stream, P, t, rp);
    hipLaunchKernelGGL(k_lstm<2>, dim3(256), dim3(512), 0, stream, P, t, rp);
    hipLaunchKernelGGL(k_qproj,   dim3(256), dim3(512), 0, stream, P, rp);
    hipLaunchKernelGGL(k_attn,    dim3(256), dim3(512), 0, stream, P, rp);
    hipLaunchKernelGGL(k_out,     dim3(256), dim3(512), 0, stream, P, t, rp);
  }
}